// Round 1
// baseline (752.387 us; speedup 1.0000x reference)
//
#include <hip/hip_runtime.h>
#include <cstdint>
#include <cstddef>

#define D 128
#define ALPHA 0.2f

// ---------------------------------------------------------------------------
// Kernel 1: h = inputs @ W   (fp32, [N,128] = [N,128] @ [128,128])
// Block: 256 threads = 16x16; tile 64 rows x 128 cols; 4x8 micro-tile.
// A rows staged in LDS (padded stride 132 to break bank conflicts on the
// row-broadcast reads); W read from global (64 KB, L1/L2 resident).
// ---------------------------------------------------------------------------
__global__ __launch_bounds__(256) void gemm_h_kernel(const float* __restrict__ A,
                                                     const float* __restrict__ W,
                                                     float* __restrict__ H,
                                                     int N) {
    __shared__ float Al[64][132];   // 33792 B
    const int tid = threadIdx.x;
    const int tx = tid & 15;        // col group: cols tx*8 .. tx*8+7
    const int ty = tid >> 4;        // row group: rows ty*4 .. ty*4+3
    const int r0 = blockIdx.x * 64;

    // stage 64 rows of A (zero-pad past N)
    for (int i = tid; i < 64 * 32; i += 256) {
        int r = i >> 5;
        int c4 = (i & 31) * 4;
        float4 v = make_float4(0.f, 0.f, 0.f, 0.f);
        if (r0 + r < N) v = *(const float4*)(A + (size_t)(r0 + r) * D + c4);
        *(float4*)&Al[r][c4] = v;
    }
    __syncthreads();

    float acc[4][8];
#pragma unroll
    for (int i = 0; i < 4; ++i)
#pragma unroll
        for (int j = 0; j < 8; ++j) acc[i][j] = 0.f;

    const int c0 = tx * 8;
    for (int k = 0; k < D; k += 4) {
        float4 av[4];
#pragma unroll
        for (int i = 0; i < 4; ++i) av[i] = *(const float4*)&Al[ty * 4 + i][k];
#pragma unroll
        for (int kk = 0; kk < 4; ++kk) {
            float4 w0 = *(const float4*)(W + (size_t)(k + kk) * D + c0);
            float4 w1 = *(const float4*)(W + (size_t)(k + kk) * D + c0 + 4);
            float wv[8] = {w0.x, w0.y, w0.z, w0.w, w1.x, w1.y, w1.z, w1.w};
#pragma unroll
            for (int i = 0; i < 4; ++i) {
                float a_ = (kk == 0) ? av[i].x : (kk == 1) ? av[i].y : (kk == 2) ? av[i].z : av[i].w;
#pragma unroll
                for (int j = 0; j < 8; ++j) acc[i][j] = fmaf(a_, wv[j], acc[i][j]);
            }
        }
    }

#pragma unroll
    for (int i = 0; i < 4; ++i) {
        int r = r0 + ty * 4 + i;
        if (r < N) {
            *(float4*)(H + (size_t)r * D + c0) =
                make_float4(acc[i][0], acc[i][1], acc[i][2], acc[i][3]);
            *(float4*)(H + (size_t)r * D + c0 + 4) =
                make_float4(acc[i][4], acc[i][5], acc[i][6], acc[i][7]);
        }
    }
}

// ---------------------------------------------------------------------------
// Kernel 2: per-edge attention + atomic scatter-accumulate.
// One 64-lane wave per edge; lane l owns features 2l, 2l+1.
// ---------------------------------------------------------------------------
__global__ __launch_bounds__(256) void edge_kernel(const float* __restrict__ H,
                                                   const int* __restrict__ src,
                                                   const int* __restrict__ dst,
                                                   const float* __restrict__ a,
                                                   float* __restrict__ acc,
                                                   float* __restrict__ rowsum,
                                                   int E) {
    int wid = (blockIdx.x << 2) + (threadIdx.x >> 6);
    if (wid >= E) return;
    int lane = threadIdx.x & 63;

    int s = src[wid];
    int d = dst[wid];

    float2 vs = *(const float2*)(H + (size_t)s * D + lane * 2);
    float2 vd = *(const float2*)(H + (size_t)d * D + lane * 2);
    float2 av = *(const float2*)(a + lane * 2);

    float sx = vs.x + vd.x;
    float sy = vs.y + vd.y;
    sx = sx > 0.f ? sx : ALPHA * sx;
    sy = sy > 0.f ? sy : ALPHA * sy;
    float dot = fmaf(sx, av.x, sy * av.y);

#pragma unroll
    for (int off = 32; off > 0; off >>= 1) dot += __shfl_xor(dot, off);

    float e = __expf(dot);

    float* accp = acc + (size_t)s * D + lane * 2;
    atomicAdd(accp, e * vd.x);
    atomicAdd(accp + 1, e * vd.y);
    if (lane == 0) atomicAdd(rowsum + s, e);
}

// ---------------------------------------------------------------------------
// Kernel 3: out = relu(acc / rowsum)
// ---------------------------------------------------------------------------
__global__ __launch_bounds__(256) void finalize_kernel(const float* __restrict__ acc,
                                                       const float* __restrict__ rowsum,
                                                       float* __restrict__ out,
                                                       int total4) {
    int i = blockIdx.x * blockDim.x + threadIdx.x;
    if (i >= total4) return;
    int row = i >> 5;  // (i*4)/128
    float inv = 1.0f / rowsum[row];
    float4 v = ((const float4*)acc)[i];
    v.x = fmaxf(v.x * inv, 0.f);
    v.y = fmaxf(v.y * inv, 0.f);
    v.z = fmaxf(v.z * inv, 0.f);
    v.w = fmaxf(v.w * inv, 0.f);
    ((float4*)out)[i] = v;
}

extern "C" void kernel_launch(void* const* d_in, const int* in_sizes, int n_in,
                              void* d_out, int out_size, void* d_ws, size_t ws_size,
                              hipStream_t stream) {
    const float* inputs = (const float*)d_in[0];
    const int* edge = (const int*)d_in[1];
    const float* W = (const float*)d_in[2];
    const float* a = (const float*)d_in[3];
    float* out = (float*)d_out;

    const int N = in_sizes[0] / D;   // 50000
    const int E = in_sizes[1] / 2;   // 800000

    float* h = (float*)d_ws;                       // [N, 128]
    float* acc = h + (size_t)N * D;                // [N, 128]
    float* rowsum = acc + (size_t)N * D;           // [N]

    // zero the accumulators (poisoned 0xAA once; also must clear between replays)
    hipMemsetAsync(acc, 0, ((size_t)N * D + N) * sizeof(float), stream);

    gemm_h_kernel<<<(N + 63) / 64, 256, 0, stream>>>(inputs, W, h, N);
    edge_kernel<<<(E + 3) / 4, 256, 0, stream>>>(h, edge, edge + E, a, acc, rowsum, E);
    finalize_kernel<<<((N * D / 4) + 255) / 256, 256, 0, stream>>>(acc, rowsum, out, N * D / 4);
}

// Round 2
// 325.392 us; speedup vs baseline: 2.3122x; 2.3122x over previous
//
#include <hip/hip_runtime.h>
#include <cstdint>
#include <cstddef>

#define D 128
#define ALPHA 0.2f
#define SCAN_T 1024

// ---------------------------------------------------------------------------
// Kernel 1: h = inputs @ W   (fp32, [N,128] = [N,128] @ [128,128])
// ---------------------------------------------------------------------------
__global__ __launch_bounds__(256) void gemm_h_kernel(const float* __restrict__ A,
                                                     const float* __restrict__ W,
                                                     float* __restrict__ H,
                                                     int N) {
    __shared__ float Al[64][132];
    const int tid = threadIdx.x;
    const int tx = tid & 15;
    const int ty = tid >> 4;
    const int r0 = blockIdx.x * 64;

    for (int i = tid; i < 64 * 32; i += 256) {
        int r = i >> 5;
        int c4 = (i & 31) * 4;
        float4 v = make_float4(0.f, 0.f, 0.f, 0.f);
        if (r0 + r < N) v = *(const float4*)(A + (size_t)(r0 + r) * D + c4);
        *(float4*)&Al[r][c4] = v;
    }
    __syncthreads();

    float acc[4][8];
#pragma unroll
    for (int i = 0; i < 4; ++i)
#pragma unroll
        for (int j = 0; j < 8; ++j) acc[i][j] = 0.f;

    const int c0 = tx * 8;
    for (int k = 0; k < D; k += 4) {
        float4 av[4];
#pragma unroll
        for (int i = 0; i < 4; ++i) av[i] = *(const float4*)&Al[ty * 4 + i][k];
#pragma unroll
        for (int kk = 0; kk < 4; ++kk) {
            float4 w0 = *(const float4*)(W + (size_t)(k + kk) * D + c0);
            float4 w1 = *(const float4*)(W + (size_t)(k + kk) * D + c0 + 4);
            float wv[8] = {w0.x, w0.y, w0.z, w0.w, w1.x, w1.y, w1.z, w1.w};
#pragma unroll
            for (int i = 0; i < 4; ++i) {
                float a_ = (kk == 0) ? av[i].x : (kk == 1) ? av[i].y : (kk == 2) ? av[i].z : av[i].w;
#pragma unroll
                for (int j = 0; j < 8; ++j) acc[i][j] = fmaf(a_, wv[j], acc[i][j]);
            }
        }
    }

#pragma unroll
    for (int i = 0; i < 4; ++i) {
        int r = r0 + ty * 4 + i;
        if (r < N) {
            *(float4*)(H + (size_t)r * D + c0) =
                make_float4(acc[i][0], acc[i][1], acc[i][2], acc[i][3]);
            *(float4*)(H + (size_t)r * D + c0 + 4) =
                make_float4(acc[i][4], acc[i][5], acc[i][6], acc[i][7]);
        }
    }
}

// ---------------------------------------------------------------------------
// CSR construction: histogram -> exclusive scan -> scatter
// ---------------------------------------------------------------------------
__global__ __launch_bounds__(256) void hist_kernel(const int* __restrict__ src,
                                                   int* __restrict__ counts, int E) {
    int i = blockIdx.x * blockDim.x + threadIdx.x;
    int stride = gridDim.x * blockDim.x;
    for (; i < E; i += stride) atomicAdd(&counts[src[i]], 1);
}

__global__ __launch_bounds__(SCAN_T) void scan_kernel(const int* __restrict__ counts,
                                                      int* __restrict__ starts,
                                                      int* __restrict__ cursor, int N) {
    __shared__ int tot[SCAN_T];
    const int t = threadIdx.x;
    const int chunk = (N + SCAN_T - 1) / SCAN_T;
    const int b0 = t * chunk;
    const int b1 = min(b0 + chunk, N);

    int sum = 0;
    for (int i = b0; i < b1; ++i) sum += counts[i];
    tot[t] = sum;

    int x = sum;
    for (int off = 1; off < SCAN_T; off <<= 1) {
        __syncthreads();
        int y = (t >= off) ? tot[t - off] : 0;
        __syncthreads();
        x += y;
        tot[t] = x;
    }

    int running = x - sum;  // exclusive prefix for this chunk
    for (int i = b0; i < b1; ++i) {
        starts[i] = running;
        cursor[i] = running;
        running += counts[i];
    }
    if (N >= b0 && N < b0 + chunk) starts[N] = running;  // = E
}

__global__ __launch_bounds__(256) void scatter_kernel(const int* __restrict__ src,
                                                      int* __restrict__ cursor,
                                                      int* __restrict__ order, int E) {
    int i = blockIdx.x * blockDim.x + threadIdx.x;
    int stride = gridDim.x * blockDim.x;
    for (; i < E; i += stride) {
        int pos = atomicAdd(&cursor[src[i]], 1);
        order[pos] = i;
    }
}

// ---------------------------------------------------------------------------
// Kernel 5: one wave per node. Registers hold the accumulator; each output
// row written exactly once. Edge IDs + dst IDs prefetched 64-wide per chunk.
// ---------------------------------------------------------------------------
__global__ __launch_bounds__(256) void node_kernel(const float* __restrict__ H,
                                                   const int* __restrict__ starts,
                                                   const int* __restrict__ order,
                                                   const int* __restrict__ dst,
                                                   const float* __restrict__ a,
                                                   float* __restrict__ out, int N) {
    int node = (blockIdx.x << 2) + (threadIdx.x >> 6);
    if (node >= N) return;
    int lane = threadIdx.x & 63;

    int beg = starts[node];
    int end = starts[node + 1];

    float2 hs = *(const float2*)(H + (size_t)node * D + lane * 2);
    float2 av = *(const float2*)(a + lane * 2);

    float accx = 0.f, accy = 0.f, rs = 0.f;

    for (int base = beg; base < end; base += 64) {
        int nchunk = min(64, end - base);
        int dt = 0;
        if (lane < nchunk) dt = dst[order[base + lane]];

        int j = 0;
        for (; j + 1 < nchunk; j += 2) {
            int d0 = __shfl(dt, j);
            int d1 = __shfl(dt, j + 1);
            float2 h0 = *(const float2*)(H + (size_t)d0 * D + lane * 2);
            float2 h1 = *(const float2*)(H + (size_t)d1 * D + lane * 2);

            float s0x = hs.x + h0.x, s0y = hs.y + h0.y;
            float s1x = hs.x + h1.x, s1y = hs.y + h1.y;
            s0x = s0x > 0.f ? s0x : ALPHA * s0x;
            s0y = s0y > 0.f ? s0y : ALPHA * s0y;
            s1x = s1x > 0.f ? s1x : ALPHA * s1x;
            s1y = s1y > 0.f ? s1y : ALPHA * s1y;
            float dot0 = fmaf(s0x, av.x, s0y * av.y);
            float dot1 = fmaf(s1x, av.x, s1y * av.y);
#pragma unroll
            for (int off = 32; off > 0; off >>= 1) {
                dot0 += __shfl_xor(dot0, off);
                dot1 += __shfl_xor(dot1, off);
            }
            float e0 = __expf(dot0);
            float e1 = __expf(dot1);
            accx = fmaf(e0, h0.x, accx);
            accy = fmaf(e0, h0.y, accy);
            rs += e0;
            accx = fmaf(e1, h1.x, accx);
            accy = fmaf(e1, h1.y, accy);
            rs += e1;
        }
        if (j < nchunk) {
            int d0 = __shfl(dt, j);
            float2 h0 = *(const float2*)(H + (size_t)d0 * D + lane * 2);
            float s0x = hs.x + h0.x, s0y = hs.y + h0.y;
            s0x = s0x > 0.f ? s0x : ALPHA * s0x;
            s0y = s0y > 0.f ? s0y : ALPHA * s0y;
            float dot0 = fmaf(s0x, av.x, s0y * av.y);
#pragma unroll
            for (int off = 32; off > 0; off >>= 1) dot0 += __shfl_xor(dot0, off);
            float e0 = __expf(dot0);
            accx = fmaf(e0, h0.x, accx);
            accy = fmaf(e0, h0.y, accy);
            rs += e0;
        }
    }

    float inv = 1.0f / rs;
    float2 o;
    o.x = fmaxf(accx * inv, 0.f);
    o.y = fmaxf(accy * inv, 0.f);
    *(float2*)(out + (size_t)node * D + lane * 2) = o;
}

extern "C" void kernel_launch(void* const* d_in, const int* in_sizes, int n_in,
                              void* d_out, int out_size, void* d_ws, size_t ws_size,
                              hipStream_t stream) {
    const float* inputs = (const float*)d_in[0];
    const int* edge = (const int*)d_in[1];
    const float* W = (const float*)d_in[2];
    const float* a = (const float*)d_in[3];
    float* out = (float*)d_out;

    const int N = in_sizes[0] / D;   // 50000
    const int E = in_sizes[1] / 2;   // 800000

    const int* src = edge;
    const int* dst = edge + E;

    float* h = (float*)d_ws;                         // [N*D]
    int* counts = (int*)(h + (size_t)N * D);         // [N]
    int* starts = counts + N;                        // [N+1]
    int* cursor = starts + N + 1;                    // [N]
    int* order = cursor + N;                         // [E]

    hipMemsetAsync(counts, 0, (size_t)N * sizeof(int), stream);

    gemm_h_kernel<<<(N + 63) / 64, 256, 0, stream>>>(inputs, W, h, N);
    hist_kernel<<<1024, 256, 0, stream>>>(src, counts, E);
    scan_kernel<<<1, SCAN_T, 0, stream>>>(counts, starts, cursor, N);
    scatter_kernel<<<1024, 256, 0, stream>>>(src, cursor, order, E);
    node_kernel<<<(N + 3) / 4, 256, 0, stream>>>(h, starts, order, dst, a, out, N);
}

// Round 3
// 210.294 us; speedup vs baseline: 3.5778x; 1.5473x over previous
//
#include <hip/hip_runtime.h>
#include <cstdint>
#include <cstddef>

#define D 128
#define ALPHA 0.2f

// ---------------------------------------------------------------------------
// Kernel 1: h = inputs @ W   (fp32, [N,128] = [N,128] @ [128,128])
// ---------------------------------------------------------------------------
__global__ __launch_bounds__(256) void gemm_h_kernel(const float* __restrict__ A,
                                                     const float* __restrict__ W,
                                                     float* __restrict__ H,
                                                     int N) {
    __shared__ float Al[64][132];
    const int tid = threadIdx.x;
    const int tx = tid & 15;
    const int ty = tid >> 4;
    const int r0 = blockIdx.x * 64;

    for (int i = tid; i < 64 * 32; i += 256) {
        int r = i >> 5;
        int c4 = (i & 31) * 4;
        float4 v = make_float4(0.f, 0.f, 0.f, 0.f);
        if (r0 + r < N) v = *(const float4*)(A + (size_t)(r0 + r) * D + c4);
        *(float4*)&Al[r][c4] = v;
    }
    __syncthreads();

    float acc[4][8];
#pragma unroll
    for (int i = 0; i < 4; ++i)
#pragma unroll
        for (int j = 0; j < 8; ++j) acc[i][j] = 0.f;

    const int c0 = tx * 8;
    for (int k = 0; k < D; k += 4) {
        float4 av[4];
#pragma unroll
        for (int i = 0; i < 4; ++i) av[i] = *(const float4*)&Al[ty * 4 + i][k];
#pragma unroll
        for (int kk = 0; kk < 4; ++kk) {
            float4 w0 = *(const float4*)(W + (size_t)(k + kk) * D + c0);
            float4 w1 = *(const float4*)(W + (size_t)(k + kk) * D + c0 + 4);
            float wv[8] = {w0.x, w0.y, w0.z, w0.w, w1.x, w1.y, w1.z, w1.w};
#pragma unroll
            for (int i = 0; i < 4; ++i) {
                float a_ = (kk == 0) ? av[i].x : (kk == 1) ? av[i].y : (kk == 2) ? av[i].z : av[i].w;
#pragma unroll
                for (int j = 0; j < 8; ++j) acc[i][j] = fmaf(a_, wv[j], acc[i][j]);
            }
        }
    }

#pragma unroll
    for (int i = 0; i < 4; ++i) {
        int r = r0 + ty * 4 + i;
        if (r < N) {
            *(float4*)(H + (size_t)r * D + c0) =
                make_float4(acc[i][0], acc[i][1], acc[i][2], acc[i][3]);
            *(float4*)(H + (size_t)r * D + c0 + 4) =
                make_float4(acc[i][4], acc[i][5], acc[i][6], acc[i][7]);
        }
    }
}

// ---------------------------------------------------------------------------
// CSR construction: histogram -> hierarchical exclusive scan -> scatter
// ---------------------------------------------------------------------------
__global__ __launch_bounds__(256) void hist_kernel(const int* __restrict__ src,
                                                   int* __restrict__ counts, int E) {
    int i = blockIdx.x * blockDim.x + threadIdx.x;
    int stride = gridDim.x * blockDim.x;
    for (; i < E; i += stride) atomicAdd(&counts[src[i]], 1);
}

// partial sums: block b -> sum(counts[b*256 .. b*256+255])
__global__ __launch_bounds__(256) void scan_partial_kernel(const int* __restrict__ counts,
                                                           int* __restrict__ blocksum, int N) {
    __shared__ int wsum[4];
    int tid = threadIdx.x;
    int i = blockIdx.x * 256 + tid;
    int x = (i < N) ? counts[i] : 0;
#pragma unroll
    for (int off = 32; off > 0; off >>= 1) x += __shfl_down(x, off);
    if ((tid & 63) == 0) wsum[tid >> 6] = x;
    __syncthreads();
    if (tid == 0) blocksum[blockIdx.x] = wsum[0] + wsum[1] + wsum[2] + wsum[3];
}

// exclusive scan of blocksum[0..nblk) (nblk <= 256), one block
__global__ __launch_bounds__(256) void scan_top_kernel(const int* __restrict__ blocksum,
                                                       int* __restrict__ blockoff, int nblk) {
    __shared__ int wsum[4];
    int tid = threadIdx.x;
    int lane = tid & 63, w = tid >> 6;
    int v = (tid < nblk) ? blocksum[tid] : 0;
    int x = v;
#pragma unroll
    for (int off = 1; off < 64; off <<= 1) {
        int y = __shfl_up(x, off);
        if (lane >= off) x += y;
    }
    if (lane == 63) wsum[w] = x;
    __syncthreads();
    int woff = 0;
    for (int i = 0; i < w; ++i) woff += wsum[i];
    if (tid < nblk) blockoff[tid] = woff + x - v;
}

// final: starts[i] = blockoff[b] + in-block exclusive prefix; cursor too
__global__ __launch_bounds__(256) void scan_final_kernel(const int* __restrict__ counts,
                                                         const int* __restrict__ blockoff,
                                                         int* __restrict__ starts,
                                                         int* __restrict__ cursor, int N) {
    __shared__ int wsum[4];
    int tid = threadIdx.x;
    int lane = tid & 63, w = tid >> 6;
    int i = blockIdx.x * 256 + tid;
    int c = (i < N) ? counts[i] : 0;
    int x = c;
#pragma unroll
    for (int off = 1; off < 64; off <<= 1) {
        int y = __shfl_up(x, off);
        if (lane >= off) x += y;
    }
    if (lane == 63) wsum[w] = x;
    __syncthreads();
    int woff = blockoff[blockIdx.x];
    for (int j = 0; j < w; ++j) woff += wsum[j];
    int pre = woff + x - c;
    if (i < N) {
        starts[i] = pre;
        cursor[i] = pre;
        if (i == N - 1) starts[N] = pre + c;
    }
}

// scatter dst VALUES into CSR order (no order[] indirection later)
__global__ __launch_bounds__(256) void scatter_kernel(const int* __restrict__ src,
                                                      const int* __restrict__ dst,
                                                      int* __restrict__ cursor,
                                                      int* __restrict__ dsts_sorted, int E) {
    int i = blockIdx.x * blockDim.x + threadIdx.x;
    int stride = gridDim.x * blockDim.x;
    for (; i < E; i += stride) {
        int pos = atomicAdd(&cursor[src[i]], 1);
        dsts_sorted[pos] = dst[i];
    }
}

// ---------------------------------------------------------------------------
// Node kernel: one wave per node; register accumulators; single row write.
// ---------------------------------------------------------------------------
__global__ __launch_bounds__(256) void node_kernel(const float* __restrict__ H,
                                                   const int* __restrict__ starts,
                                                   const int* __restrict__ dsts_sorted,
                                                   const float* __restrict__ a,
                                                   float* __restrict__ out, int N) {
    int node = (blockIdx.x << 2) + (threadIdx.x >> 6);
    if (node >= N) return;
    int lane = threadIdx.x & 63;

    int beg = starts[node];
    int end = starts[node + 1];

    float2 hs = *(const float2*)(H + (size_t)node * D + lane * 2);
    float2 av = *(const float2*)(a + lane * 2);

    float accx = 0.f, accy = 0.f, rs = 0.f;

    for (int base = beg; base < end; base += 64) {
        int nchunk = min(64, end - base);
        int dt = 0;
        if (lane < nchunk) dt = dsts_sorted[base + lane];

        int j = 0;
        for (; j + 1 < nchunk; j += 2) {
            int d0 = __shfl(dt, j);
            int d1 = __shfl(dt, j + 1);
            float2 h0 = *(const float2*)(H + (size_t)d0 * D + lane * 2);
            float2 h1 = *(const float2*)(H + (size_t)d1 * D + lane * 2);

            float s0x = hs.x + h0.x, s0y = hs.y + h0.y;
            float s1x = hs.x + h1.x, s1y = hs.y + h1.y;
            s0x = s0x > 0.f ? s0x : ALPHA * s0x;
            s0y = s0y > 0.f ? s0y : ALPHA * s0y;
            s1x = s1x > 0.f ? s1x : ALPHA * s1x;
            s1y = s1y > 0.f ? s1y : ALPHA * s1y;
            float dot0 = fmaf(s0x, av.x, s0y * av.y);
            float dot1 = fmaf(s1x, av.x, s1y * av.y);
#pragma unroll
            for (int off = 32; off > 0; off >>= 1) {
                dot0 += __shfl_xor(dot0, off);
                dot1 += __shfl_xor(dot1, off);
            }
            float e0 = __expf(dot0);
            float e1 = __expf(dot1);
            accx = fmaf(e0, h0.x, accx);
            accy = fmaf(e0, h0.y, accy);
            rs += e0;
            accx = fmaf(e1, h1.x, accx);
            accy = fmaf(e1, h1.y, accy);
            rs += e1;
        }
        if (j < nchunk) {
            int d0 = __shfl(dt, j);
            float2 h0 = *(const float2*)(H + (size_t)d0 * D + lane * 2);
            float s0x = hs.x + h0.x, s0y = hs.y + h0.y;
            s0x = s0x > 0.f ? s0x : ALPHA * s0x;
            s0y = s0y > 0.f ? s0y : ALPHA * s0y;
            float dot0 = fmaf(s0x, av.x, s0y * av.y);
#pragma unroll
            for (int off = 32; off > 0; off >>= 1) dot0 += __shfl_xor(dot0, off);
            float e0 = __expf(dot0);
            accx = fmaf(e0, h0.x, accx);
            accy = fmaf(e0, h0.y, accy);
            rs += e0;
        }
    }

    float inv = 1.0f / rs;
    float2 o;
    o.x = fmaxf(accx * inv, 0.f);
    o.y = fmaxf(accy * inv, 0.f);
    *(float2*)(out + (size_t)node * D + lane * 2) = o;
}

extern "C" void kernel_launch(void* const* d_in, const int* in_sizes, int n_in,
                              void* d_out, int out_size, void* d_ws, size_t ws_size,
                              hipStream_t stream) {
    const float* inputs = (const float*)d_in[0];
    const int* edge = (const int*)d_in[1];
    const float* W = (const float*)d_in[2];
    const float* a = (const float*)d_in[3];
    float* out = (float*)d_out;

    const int N = in_sizes[0] / D;   // 50000
    const int E = in_sizes[1] / 2;   // 800000

    const int* src = edge;
    const int* dst = edge + E;

    float* h = (float*)d_ws;                         // [N*D]
    int* counts = (int*)(h + (size_t)N * D);         // [N]
    int* starts = counts + N;                        // [N+1]
    int* cursor = starts + N + 1;                    // [N]
    int* blocksum = cursor + N;                      // [256]
    int* blockoff = blocksum + 256;                  // [256]
    int* dsts_sorted = blockoff + 256;               // [E]

    const int nblk = (N + 255) / 256;                // 196 (fits scan_top's 256)

    hipMemsetAsync(counts, 0, (size_t)N * sizeof(int), stream);

    gemm_h_kernel<<<(N + 63) / 64, 256, 0, stream>>>(inputs, W, h, N);
    hist_kernel<<<1024, 256, 0, stream>>>(src, counts, E);
    scan_partial_kernel<<<nblk, 256, 0, stream>>>(counts, blocksum, N);
    scan_top_kernel<<<1, 256, 0, stream>>>(blocksum, blockoff, nblk);
    scan_final_kernel<<<nblk, 256, 0, stream>>>(counts, blockoff, starts, cursor, N);
    scatter_kernel<<<1024, 256, 0, stream>>>(src, dst, cursor, dsts_sorted, E);
    node_kernel<<<(N + 3) / 4, 256, 0, stream>>>(h, starts, dsts_sorted, a, out, N);
}

// Round 4
// 183.120 us; speedup vs baseline: 4.1087x; 1.1484x over previous
//
#include <hip/hip_runtime.h>
#include <cstdint>
#include <cstddef>

#define D 128
#define ALPHA 0.2f

typedef __attribute__((ext_vector_type(8))) short short8_t;   // 8 x bf16
typedef __attribute__((ext_vector_type(4))) float f32x4_t;

static __device__ __forceinline__ ushort f2bf(float f) {
    union { float f; uint32_t u; } v; v.f = f;
    uint32_t r = (v.u + 0x7FFFu + ((v.u >> 16) & 1u)) >> 16;
    return (ushort)r;
}

// ---------------------------------------------------------------------------
// Kernel 0: W [128][128] fp32 -> Wt [n][k] bf16 (transposed)
// ---------------------------------------------------------------------------
__global__ __launch_bounds__(256) void w_prep_kernel(const float* __restrict__ W,
                                                     ushort* __restrict__ Wt) {
    int idx = blockIdx.x * 256 + threadIdx.x;   // 0..16383
    int k = idx >> 7;
    int n = idx & 127;
    Wt[n * 128 + k] = f2bf(W[idx]);
}

// ---------------------------------------------------------------------------
// Kernel 1: H = A @ W via bf16 MFMA (fp32 accum/output).
// Block 256 = 4 waves; tile 64 rows x 128 cols; wave w -> rows (w>>1)*32,
// cols (w&1)*64. A staged bf16 in LDS (stride 136 -> 2-way conflicts only).
// B-frags from global Wt (32 KB, L1-resident).
// ---------------------------------------------------------------------------
__global__ __launch_bounds__(256) void gemm_h_kernel(const float* __restrict__ A,
                                                     const ushort* __restrict__ Wt,
                                                     float* __restrict__ H,
                                                     int N) {
    __shared__ ushort Alds[64][136];
    const int tid = threadIdx.x;
    const int r0 = blockIdx.x * 64;

    // stage 64 rows of A as bf16
#pragma unroll
    for (int it = 0; it < 8; ++it) {
        int idx = it * 256 + tid;          // 0..2047
        int r = idx >> 5;
        int c4 = (idx & 31) * 4;
        float4 v = make_float4(0.f, 0.f, 0.f, 0.f);
        if (r0 + r < N) v = *(const float4*)(A + (size_t)(r0 + r) * D + c4);
        ushort4 b;
        b.x = f2bf(v.x); b.y = f2bf(v.y); b.z = f2bf(v.z); b.w = f2bf(v.w);
        *(ushort4*)&Alds[r][c4] = b;
    }
    __syncthreads();

    const int lane = tid & 63;
    const int w = tid >> 6;
    const int wm = w >> 1;     // 0/1 -> row half
    const int wn = w & 1;      // 0/1 -> col half
    const int l15 = lane & 15;
    const int koff = (lane >> 4) * 8;

    f32x4_t acc[2][4];
#pragma unroll
    for (int mt = 0; mt < 2; ++mt)
#pragma unroll
        for (int nt = 0; nt < 4; ++nt) acc[mt][nt] = (f32x4_t){0.f, 0.f, 0.f, 0.f};

    const int arow = wm * 32 + l15;
#pragma unroll
    for (int kk = 0; kk < 4; ++kk) {
        short8_t am0 = *(const short8_t*)&Alds[arow][kk * 32 + koff];
        short8_t am1 = *(const short8_t*)&Alds[arow + 16][kk * 32 + koff];
        short8_t bn[4];
#pragma unroll
        for (int nt = 0; nt < 4; ++nt)
            bn[nt] = *(const short8_t*)(Wt + (size_t)(wn * 64 + nt * 16 + l15) * 128 + kk * 32 + koff);
#pragma unroll
        for (int nt = 0; nt < 4; ++nt) {
            acc[0][nt] = __builtin_amdgcn_mfma_f32_16x16x32_bf16(am0, bn[nt], acc[0][nt], 0, 0, 0);
            acc[1][nt] = __builtin_amdgcn_mfma_f32_16x16x32_bf16(am1, bn[nt], acc[1][nt], 0, 0, 0);
        }
    }

    const int crow = (lane >> 4) * 4;
#pragma unroll
    for (int mt = 0; mt < 2; ++mt)
#pragma unroll
        for (int nt = 0; nt < 4; ++nt)
#pragma unroll
            for (int r = 0; r < 4; ++r) {
                int row = r0 + wm * 32 + mt * 16 + crow + r;
                if (row < N)
                    H[(size_t)row * D + wn * 64 + nt * 16 + l15] = acc[mt][nt][r];
            }
}

// ---------------------------------------------------------------------------
// CSR construction: histogram -> hierarchical exclusive scan -> scatter
// ---------------------------------------------------------------------------
__global__ __launch_bounds__(256) void hist_kernel(const int* __restrict__ src,
                                                   int* __restrict__ counts, int E) {
    int i = blockIdx.x * blockDim.x + threadIdx.x;
    int stride = gridDim.x * blockDim.x;
    for (; i < E; i += stride) atomicAdd(&counts[src[i]], 1);
}

__global__ __launch_bounds__(256) void scan_partial_kernel(const int* __restrict__ counts,
                                                           int* __restrict__ blocksum, int N) {
    __shared__ int wsum[4];
    int tid = threadIdx.x;
    int i = blockIdx.x * 256 + tid;
    int x = (i < N) ? counts[i] : 0;
#pragma unroll
    for (int off = 32; off > 0; off >>= 1) x += __shfl_down(x, off);
    if ((tid & 63) == 0) wsum[tid >> 6] = x;
    __syncthreads();
    if (tid == 0) blocksum[blockIdx.x] = wsum[0] + wsum[1] + wsum[2] + wsum[3];
}

__global__ __launch_bounds__(256) void scan_top_kernel(const int* __restrict__ blocksum,
                                                       int* __restrict__ blockoff, int nblk) {
    __shared__ int wsum[4];
    int tid = threadIdx.x;
    int lane = tid & 63, w = tid >> 6;
    int v = (tid < nblk) ? blocksum[tid] : 0;
    int x = v;
#pragma unroll
    for (int off = 1; off < 64; off <<= 1) {
        int y = __shfl_up(x, off);
        if (lane >= off) x += y;
    }
    if (lane == 63) wsum[w] = x;
    __syncthreads();
    int woff = 0;
    for (int i = 0; i < w; ++i) woff += wsum[i];
    if (tid < nblk) blockoff[tid] = woff + x - v;
}

__global__ __launch_bounds__(256) void scan_final_kernel(const int* __restrict__ counts,
                                                         const int* __restrict__ blockoff,
                                                         int* __restrict__ starts,
                                                         int* __restrict__ cursor, int N) {
    __shared__ int wsum[4];
    int tid = threadIdx.x;
    int lane = tid & 63, w = tid >> 6;
    int i = blockIdx.x * 256 + tid;
    int c = (i < N) ? counts[i] : 0;
    int x = c;
#pragma unroll
    for (int off = 1; off < 64; off <<= 1) {
        int y = __shfl_up(x, off);
        if (lane >= off) x += y;
    }
    if (lane == 63) wsum[w] = x;
    __syncthreads();
    int woff = blockoff[blockIdx.x];
    for (int j = 0; j < w; ++j) woff += wsum[j];
    int pre = woff + x - c;
    if (i < N) {
        starts[i] = pre;
        cursor[i] = pre;
        if (i == N - 1) starts[N] = pre + c;
    }
}

__global__ __launch_bounds__(256) void scatter_kernel(const int* __restrict__ src,
                                                      const int* __restrict__ dst,
                                                      int* __restrict__ cursor,
                                                      int* __restrict__ dsts_sorted, int E) {
    int i = blockIdx.x * blockDim.x + threadIdx.x;
    int stride = gridDim.x * blockDim.x;
    for (; i < E; i += stride) {
        int pos = atomicAdd(&cursor[src[i]], 1);
        dsts_sorted[pos] = dst[i];
    }
}

// ---------------------------------------------------------------------------
// Node kernel: one wave per node. Per 16-edge chunk: 16 gather loads in
// flight, per-lane partial dots, multi-value butterfly reduce (lane l ends
// with the dot of edge bitrev4(l&15)), one exp per lane, 16 broadcasts.
// ---------------------------------------------------------------------------
__global__ __launch_bounds__(256) void node_kernel(const float* __restrict__ H,
                                                   const int* __restrict__ starts,
                                                   const int* __restrict__ dsts_sorted,
                                                   const float* __restrict__ a,
                                                   float* __restrict__ out, int N) {
    int node = (blockIdx.x << 2) + (threadIdx.x >> 6);
    if (node >= N) return;
    int lane = threadIdx.x & 63;

    int beg = starts[node];
    int end = starts[node + 1];

    float2 hs = *(const float2*)(H + (size_t)node * D + lane * 2);
    float2 av = *(const float2*)(a + lane * 2);

    float accx = 0.f, accy = 0.f, rs = 0.f;

    for (int base = beg; base < end; base += 64) {
        int n64 = min(64, end - base);
        int dt = (lane < n64) ? dsts_sorted[base + lane] : 0;

        for (int c = 0; c * 16 < n64; ++c) {
            int cnt = min(16, n64 - c * 16);

            float2 hv[16];
            float p[16];
            // issue all gathers for this chunk
#pragma unroll
            for (int j = 0; j < 16; ++j) {
                int dj = __shfl(dt, c * 16 + j);
                if (j < cnt)
                    hv[j] = *(const float2*)(H + (size_t)dj * D + lane * 2);
                else
                    hv[j] = make_float2(0.f, 0.f);
            }
            // per-lane partial dots
#pragma unroll
            for (int j = 0; j < 16; ++j) {
                float sx = hs.x + hv[j].x;
                float sy = hs.y + hv[j].y;
                sx = sx > 0.f ? sx : ALPHA * sx;
                sy = sy > 0.f ? sy : ALPHA * sy;
                p[j] = (j < cnt) ? fmaf(sx, av.x, sy * av.y) : 0.f;
            }
            // butterfly multi-reduce: 16 values -> 1 per lane
            {
                bool hi = lane & 1;
#pragma unroll
                for (int i = 0; i < 8; ++i) {
                    float send = hi ? p[i] : p[i + 8];
                    float recv = __shfl_xor(send, 1);
                    p[i] = (hi ? p[i + 8] : p[i]) + recv;
                }
                hi = lane & 2;
#pragma unroll
                for (int i = 0; i < 4; ++i) {
                    float send = hi ? p[i] : p[i + 4];
                    float recv = __shfl_xor(send, 2);
                    p[i] = (hi ? p[i + 4] : p[i]) + recv;
                }
                hi = lane & 4;
#pragma unroll
                for (int i = 0; i < 2; ++i) {
                    float send = hi ? p[i] : p[i + 2];
                    float recv = __shfl_xor(send, 4);
                    p[i] = (hi ? p[i + 2] : p[i]) + recv;
                }
                hi = lane & 8;
                {
                    float send = hi ? p[0] : p[1];
                    float recv = __shfl_xor(send, 8);
                    p[0] = (hi ? p[1] : p[0]) + recv;
                }
                p[0] += __shfl_xor(p[0], 16);
                p[0] += __shfl_xor(p[0], 32);
            }
            float el = __expf(p[0]);

            // broadcast e_j from lane bitrev4(j) and accumulate
            const int brev[16] = {0, 8, 4, 12, 2, 10, 6, 14, 1, 9, 5, 13, 3, 11, 7, 15};
#pragma unroll
            for (int j = 0; j < 16; ++j) {
                float ej = __shfl(el, brev[j]);
                if (j < cnt) {
                    accx = fmaf(ej, hv[j].x, accx);
                    accy = fmaf(ej, hv[j].y, accy);
                    rs += ej;
                }
            }
        }
    }

    float inv = 1.0f / rs;
    float2 o;
    o.x = fmaxf(accx * inv, 0.f);
    o.y = fmaxf(accy * inv, 0.f);
    *(float2*)(out + (size_t)node * D + lane * 2) = o;
}

extern "C" void kernel_launch(void* const* d_in, const int* in_sizes, int n_in,
                              void* d_out, int out_size, void* d_ws, size_t ws_size,
                              hipStream_t stream) {
    const float* inputs = (const float*)d_in[0];
    const int* edge = (const int*)d_in[1];
    const float* W = (const float*)d_in[2];
    const float* a = (const float*)d_in[3];
    float* out = (float*)d_out;

    const int N = in_sizes[0] / D;   // 50000
    const int E = in_sizes[1] / 2;   // 800000

    const int* src = edge;
    const int* dst = edge + E;

    // ws layout (Wt first to keep 16B alignment for short8 loads)
    ushort* wt = (ushort*)d_ws;                      // [128*128] bf16
    float* h = (float*)(wt + 128 * 128);             // [N*D] fp32
    int* counts = (int*)(h + (size_t)N * D);         // [N]
    int* starts = counts + N;                        // [N+1]
    int* cursor = starts + N + 1;                    // [N]
    int* blocksum = cursor + N;                      // [256]
    int* blockoff = blocksum + 256;                  // [256]
    int* dsts_sorted = blockoff + 256;               // [E]

    const int nblk = (N + 255) / 256;                // 196

    hipMemsetAsync(counts, 0, (size_t)N * sizeof(int), stream);

    w_prep_kernel<<<64, 256, 0, stream>>>(W, wt);
    gemm_h_kernel<<<(N + 63) / 64, 256, 0, stream>>>(inputs, wt, h, N);
    hist_kernel<<<1024, 256, 0, stream>>>(src, counts, E);
    scan_partial_kernel<<<nblk, 256, 0, stream>>>(counts, blocksum, N);
    scan_top_kernel<<<1, 256, 0, stream>>>(blocksum, blockoff, nblk);
    scan_final_kernel<<<nblk, 256, 0, stream>>>(counts, blockoff, starts, cursor, N);
    scatter_kernel<<<1024, 256, 0, stream>>>(src, dst, cursor, dsts_sorted, E);
    node_kernel<<<(N + 3) / 4, 256, 0, stream>>>(h, starts, dsts_sorted, a, out, N);
}